// Round 9
// baseline (129.059 us; speedup 1.0000x reference)
//
#include <hip/hip_runtime.h>

constexpr int BATCH = 1048576;
constexpr int H = 20;
constexpr int BLK = 256;
constexpr unsigned CAP = 32768;          // fixup list capacity (expect ~3k entries)
constexpr float EPS_GUARD = 1e-3f;       // ~10x combined fast-path cdf error bound

// ---- d_ws byte offsets (16B aligned) ----
constexpr size_t CNT_OFF  = 0;                       // u32 counter
constexpr size_t LIST_OFF = 4096;                    // u32[CAP] risky rows
constexpr size_t WFH_OFF  = 4096 + 131072;           // f16 W-frag hi: 5*64*8
constexpr size_t WFL_OFF  = WFH_OFF + 8192;          // f16 W-frag lo
constexpr size_t B4_OFF   = WFL_OFF + 8192;          // f32 bias4[80]  (4q+g)
constexpr size_t WD4_OFF  = B4_OFF + 512;            // f32 wd4[80]    (4q+a, a<3)

typedef _Float16 f16x8 __attribute__((ext_vector_type(8)));
typedef float    f32x4 __attribute__((ext_vector_type(4)));

// ---- exact path (bit-identical to validated R3/R5-R8 kernels) ----
__device__ __forceinline__ float sigmoidf_stable(float z) {
    const float e = expf(-fabsf(z));
    const float n = (z >= 0.0f) ? 1.0f : e;
    return n / (1.0f + e);
}
// ---- fast path (validated R6-R8) ----
__device__ __forceinline__ float fsigmoid(float z) {
    const float e = __expf(-z);
    return __builtin_amdgcn_rcpf(1.0f + e);
}
__device__ __forceinline__ float ftanh(float z) {
    const float e = __expf(2.0f * z);
    return 1.0f - 2.0f * __builtin_amdgcn_rcpf(e + 1.0f);
}

// =====================  weight prep  =====================
__global__ __launch_bounds__(256) void pack_weights(
    const float* __restrict__ W_ih, const float* __restrict__ W_hh,
    const float* __restrict__ b_ih, const float* __restrict__ b_hh,
    const float* __restrict__ W_dec, char* __restrict__ ws)
{
    const int idx = blockIdx.x * 256 + threadIdx.x;
    if (idx == 0) *(unsigned*)(ws + CNT_OFF) = 0u;
    if (idx < 2560) {
        // one (m, lane, j) A-fragment element. A row = l&15 -> gate-row 16m+(l&15),
        // k = (l>>4)*8 + j.  gate-row (interleaved) = 4q+g  ->  orig row g*20+q.
        const int m = idx >> 9;
        const int l = (idx >> 3) & 63;
        const int j = idx & 7;
        const int grow = 16 * m + (l & 15);
        const int q = grow >> 2, g = grow & 3;
        const int orow = g * 20 + q;
        const int k = ((l >> 4) << 3) + j;
        float wv = 0.0f;
        if (k < 20)      wv = W_hh[orow * 20 + k];
        else if (k < 22) wv = W_ih[orow * 2 + (k - 20)];
        const _Float16 hi = (_Float16)wv;
        const _Float16 lo = (_Float16)(wv - (float)hi);
        ((_Float16*)(ws + WFH_OFF))[idx] = hi;   // idx == (m*64+l)*8+j
        ((_Float16*)(ws + WFL_OFF))[idx] = lo;
    } else if (idx < 2640) {
        const int i2 = idx - 2560;
        const int q = i2 >> 2, g = i2 & 3;
        ((float*)(ws + B4_OFF))[i2] = b_ih[g * 20 + q] + b_hh[g * 20 + q];
    } else if (idx < 2720) {
        const int i2 = idx - 2640;
        const int q = i2 >> 2, a = i2 & 3;
        ((float*)(ws + WD4_OFF))[i2] = (a < 3) ? W_dec[a * 20 + q] : 0.0f;
    }
}

// =====================  main MFMA kernel  =====================
// Block = 256 rows; wave = 64 rows; fully wave-autonomous (no __syncthreads).
// LDS row (176B, 16B-aligned, 11 chunks -> conflict-free b128):
//   f16 hi[22] | f16 0[10] | f16 lo[22] | f16 0[10] | pad  -> later reused as
//   f32 h[q]@+0 and f32 c[q]@+88B for the coalesced store phase.
__global__ __launch_bounds__(256) void lstm_mfma(
    const float* __restrict__ x, const float* __restrict__ hx,
    const float* __restrict__ cx, const float* __restrict__ u,
    const char* __restrict__ ws, const float* __restrict__ b_dec,
    float* __restrict__ out, unsigned* __restrict__ cnt,
    unsigned* __restrict__ list)
{
    __shared__ char smem[256 * 176];
    const int t = threadIdx.x;
    const int lane = t & 63;
    const int w = t >> 6;
    const int b0 = blockIdx.x * 256;

    // ---- stage A-tile row t (own wave's rows only) ----
    {
        const float* hxr = hx + (size_t)(b0 + t) * H;
        float v[22];
#pragma unroll
        for (int jj = 0; jj < 5; ++jj) {
            const float4 q4 = *(const float4*)(hxr + 4 * jj);
            v[4 * jj] = q4.x; v[4 * jj + 1] = q4.y;
            v[4 * jj + 2] = q4.z; v[4 * jj + 3] = q4.w;
        }
        const float2 xv = *(const float2*)(x + 2 * (size_t)(b0 + t));
        v[20] = xv.x; v[21] = xv.y;
        unsigned uh[11], ul[11];
#pragma unroll
        for (int i = 0; i < 11; ++i) {
            const _Float16 h0 = (_Float16)v[2 * i];
            const _Float16 h1 = (_Float16)v[2 * i + 1];
            const _Float16 l0_ = (_Float16)(v[2 * i] - (float)h0);
            const _Float16 l1_ = (_Float16)(v[2 * i + 1] - (float)h1);
            uh[i] = (unsigned)__builtin_bit_cast(unsigned short, h0) |
                    ((unsigned)__builtin_bit_cast(unsigned short, h1) << 16);
            ul[i] = (unsigned)__builtin_bit_cast(unsigned short, l0_) |
                    ((unsigned)__builtin_bit_cast(unsigned short, l1_) << 16);
        }
        char* rp = smem + t * 176;
        *(uint4*)(rp +   0) = make_uint4(uh[0], uh[1], uh[2], uh[3]);
        *(uint4*)(rp +  16) = make_uint4(uh[4], uh[5], uh[6], uh[7]);
        *(uint2*)(rp +  32) = make_uint2(uh[8], uh[9]);
        *(unsigned*)(rp + 40) = uh[10];
        *(unsigned*)(rp + 44) = 0u;
        *(uint4*)(rp +  48) = make_uint4(0u, 0u, 0u, 0u);
        *(uint4*)(rp +  64) = make_uint4(ul[0], ul[1], ul[2], ul[3]);
        *(uint4*)(rp +  80) = make_uint4(ul[4], ul[5], ul[6], ul[7]);
        *(uint2*)(rp +  96) = make_uint2(ul[8], ul[9]);
        *(unsigned*)(rp + 104) = ul[10];
        *(unsigned*)(rp + 108) = 0u;
        *(uint4*)(rp + 112) = make_uint4(0u, 0u, 0u, 0u);
    }

    // ---- per-lane constants: W-fragments (wave-uniform data), bias, dec ----
    f16x8 wfh[5], wfl[5];
    float4 bias_m[5], wd_m[5];
#pragma unroll
    for (int m = 0; m < 5; ++m) {
        wfh[m] = *(const f16x8*)(ws + WFH_OFF + (size_t)(m * 64 + lane) * 16);
        wfl[m] = *(const f16x8*)(ws + WFL_OFF + (size_t)(m * 64 + lane) * 16);
        const int qm = 4 * m + (lane >> 4);
        bias_m[m] = *(const float4*)(ws + B4_OFF + (size_t)qm * 16);
        wd_m[m]   = *(const float4*)(ws + WD4_OFF + (size_t)qm * 16);
    }
    const float bd0 = b_dec[0], bd1 = b_dec[1], bd2 = b_dec[2];

    // ---- 4 groups of 16 rows per wave ----
#pragma unroll
    for (int g = 0; g < 4; ++g) {
        const int rloc = 64 * w + 16 * g + (lane & 15);
        const char* rp = smem + rloc * 176 + ((lane >> 4) << 4);
        const f16x8 bhi = *(const f16x8*)rp;          // B-frag: col=l&15, k-octet=l>>4
        const f16x8 blo = *(const f16x8*)(rp + 64);
        const int bg = b0 + rloc;
        float* rowf = (float*)(smem + rloc * 176);

        // hoist this group's cx gathers (L1-resident)
        float cxv_[5];
#pragma unroll
        for (int m = 0; m < 5; ++m)
            cxv_[m] = cx[(size_t)bg * H + 4 * m + (lane >> 4)];

        float l0 = 0.0f, l1 = 0.0f, l2 = 0.0f;
#pragma unroll
        for (int m = 0; m < 5; ++m) {
            f32x4 acc = {0.0f, 0.0f, 0.0f, 0.0f};
            acc = __builtin_amdgcn_mfma_f32_16x16x32_f16(wfh[m], bhi, acc, 0, 0, 0);
            acc = __builtin_amdgcn_mfma_f32_16x16x32_f16(wfh[m], blo, acc, 0, 0, 0);
            acc = __builtin_amdgcn_mfma_f32_16x16x32_f16(wfl[m], bhi, acc, 0, 0, 0);
            const int q = 4 * m + (lane >> 4);
            const float gi = fsigmoid(acc[0] + bias_m[m].x);
            const float gf = fsigmoid(acc[1] + bias_m[m].y);
            const float g2 = ftanh  (acc[2] + bias_m[m].z);
            const float go = fsigmoid(acc[3] + bias_m[m].w);
            const float cq = gf * cxv_[m] + gi * g2;
            const float hq = go * ftanh(cq);
            rowf[q] = hq;            // bytes 0..79   (bhi/blo already consumed)
            rowf[22 + q] = cq;       // bytes 88..164
            l0 += hq * wd_m[m].x;
            l1 += hq * wd_m[m].y;
            l2 += hq * wd_m[m].z;
        }
        // reduce the 4 lane-replicas of each batch row (lanes b, b+16, b+32, b+48)
        l0 += __shfl_xor(l0, 16); l0 += __shfl_xor(l0, 32);
        l1 += __shfl_xor(l1, 16); l1 += __shfl_xor(l1, 32);
        l2 += __shfl_xor(l2, 16); l2 += __shfl_xor(l2, 32);

        if (lane < 16) {
            const float L0 = l0 + bd0, L1 = l1 + bd1, L2 = l2 + bd2;
            const float uv = u[bg];
            const float mm = fmaxf(fmaxf(L0, L1), L2);
            const float ss = __expf(L0 - mm) + __expf(L1 - mm) + __expf(L2 - mm);
            const float lse = mm + __logf(ss);
            const float lp0 = L0 - lse, lp1 = L1 - lse, lp2 = L2 - lse;
            const float p0 = __expf(lp0), p1 = __expf(lp1), p2 = __expf(lp2);
            const float c0 = p0, c1 = c0 + p1, c2 = c1 + p2;
            int acti = (int)(c0 < uv) + (int)(c1 < uv) + (int)(c2 < uv);
            acti = acti > 2 ? 2 : acti;
            out[bg] = (float)acti;
            out[(size_t)BATCH + bg] = (acti == 0) ? lp0 : ((acti == 1) ? lp1 : lp2);
            const float dmin = fminf(fminf(fabsf(c0 - uv), fabsf(c1 - uv)), fabsf(c2 - uv));
            if (dmin < EPS_GUARD) {
                const unsigned i = atomicAdd(cnt, 1u);
                if (i < CAP) list[i] = (unsigned)bg;
            }
        }
    }

    // ---- wave-local coalesced store of h/c (no barrier needed) ----
    float* hout  = out + 2 * (size_t)BATCH;
    float* cout_ = hout + (size_t)H * BATCH;
    const size_t bb = (size_t)blockIdx.x * (256 * H);
#pragma unroll
    for (int jj = 0; jj < 5; ++jj) {
        const int f = 1280 * w + 4 * lane + 256 * jj;   // within this wave's span
        float4 hv4, cv4;
#pragma unroll
        for (int e = 0; e < 4; ++e) {
            const int ff = f + e;
            const int rr = ff / 20, qq = ff % 20;
            const float* rowf = (const float*)(smem + rr * 176);
            (&hv4.x)[e] = rowf[qq];
            (&cv4.x)[e] = rowf[22 + qq];
        }
        *(float4*)(hout  + bb + f) = hv4;
        *(float4*)(cout_ + bb + f) = cv4;
    }
}

// =====================  exact fixup (sparse)  =====================
__global__ __launch_bounds__(256) void lstm_fixup(
    const float* __restrict__ x, const float* __restrict__ hx,
    const float* __restrict__ cx, const float* __restrict__ u,
    const float* __restrict__ W_ih, const float* __restrict__ W_hh,
    const float* __restrict__ b_ih, const float* __restrict__ b_hh,
    const float* __restrict__ W_dec, const float* __restrict__ b_dec,
    const unsigned* __restrict__ cnt, const unsigned* __restrict__ list,
    float* __restrict__ out)
{
    const unsigned n = min(*cnt, CAP);
    const unsigned i = blockIdx.x * 256 + threadIdx.x;
    if (i >= n) return;
    const int b = (int)list[i];
    const float x0 = x[2 * (size_t)b], x1 = x[2 * (size_t)b + 1];
    const float uv = u[b];
    float hv[H], cvv[H];
#pragma unroll
    for (int k = 0; k < H; ++k) {
        hv[k]  = hx[(size_t)b * H + k];
        cvv[k] = cx[(size_t)b * H + k];
    }
    // exact libm path — expressions identical to the validated R3 kernel
    float l0 = b_dec[0], l1 = b_dec[1], l2 = b_dec[2];
#pragma unroll 1
    for (int q = 0; q < H; ++q) {
        float gi = (b_ih[q]      + b_hh[q])      + x0 * W_ih[2 * q]          + x1 * W_ih[2 * q + 1];
        float gf = (b_ih[20 + q] + b_hh[20 + q]) + x0 * W_ih[2 * (20 + q)]   + x1 * W_ih[2 * (20 + q) + 1];
        float gg = (b_ih[40 + q] + b_hh[40 + q]) + x0 * W_ih[2 * (40 + q)]   + x1 * W_ih[2 * (40 + q) + 1];
        float go = (b_ih[60 + q] + b_hh[60 + q]) + x0 * W_ih[2 * (60 + q)]   + x1 * W_ih[2 * (60 + q) + 1];
#pragma unroll
        for (int k = 0; k < H; ++k) {
            const float hk = hv[k];
            gi += hk * W_hh[(q)      * H + k];
            gf += hk * W_hh[(20 + q) * H + k];
            gg += hk * W_hh[(40 + q) * H + k];
            go += hk * W_hh[(60 + q) * H + k];
        }
        gi = sigmoidf_stable(gi);
        gf = sigmoidf_stable(gf);
        gg = tanhf(gg);
        go = sigmoidf_stable(go);
        const float cq = gf * cvv[q] + gi * gg;
        const float hq = go * tanhf(cq);
        l0 += hq * W_dec[q];
        l1 += hq * W_dec[20 + q];
        l2 += hq * W_dec[40 + q];
    }
    const float m = fmaxf(fmaxf(l0, l1), l2);
    const float s = expf(l0 - m) + expf(l1 - m) + expf(l2 - m);
    const float lse = m + logf(s);
    const float lp0 = l0 - lse, lp1 = l1 - lse, lp2 = l2 - lse;
    const float p0 = expf(lp0), p1 = expf(lp1), p2 = expf(lp2);
    const float c0 = p0, c1 = c0 + p1, c2 = c1 + p2;
    int ae = (int)(c0 < uv) + (int)(c1 < uv) + (int)(c2 < uv);
    ae = ae > 2 ? 2 : ae;
    out[b] = (float)ae;
    out[(size_t)BATCH + b] = (ae == 0) ? lp0 : ((ae == 1) ? lp1 : lp2);
}

extern "C" void kernel_launch(void* const* d_in, const int* in_sizes, int n_in,
                              void* d_out, int out_size, void* d_ws, size_t ws_size,
                              hipStream_t stream) {
    const float* x     = (const float*)d_in[0];
    const float* hx    = (const float*)d_in[1];
    const float* cx    = (const float*)d_in[2];
    const float* u     = (const float*)d_in[3];
    const float* W_ih  = (const float*)d_in[4];
    const float* W_hh  = (const float*)d_in[5];
    const float* b_ih  = (const float*)d_in[6];
    const float* b_hh  = (const float*)d_in[7];
    const float* W_dec = (const float*)d_in[8];
    const float* b_dec = (const float*)d_in[9];
    float* out = (float*)d_out;
    char* ws = (char*)d_ws;
    unsigned* cnt  = (unsigned*)(ws + CNT_OFF);
    unsigned* list = (unsigned*)(ws + LIST_OFF);

    pack_weights<<<16, 256, 0, stream>>>(W_ih, W_hh, b_ih, b_hh, W_dec, ws);
    lstm_mfma<<<BATCH / 256, 256, 0, stream>>>(x, hx, cx, u, ws, b_dec, out, cnt, list);
    lstm_fixup<<<CAP / 256, 256, 0, stream>>>(x, hx, cx, u, W_ih, W_hh, b_ih, b_hh,
                                              W_dec, b_dec, cnt, list, out);
}

// Round 10
// 117.747 us; speedup vs baseline: 1.0961x; 1.0961x over previous
//
#include <hip/hip_runtime.h>

constexpr int BATCH = 1048576;
constexpr int H = 20;       // hidden
constexpr int BLK = 256;    // threads per block = batch rows per block
constexpr int RS = 21;      // padded LDS row stride (gcd(21,32)=1 -> conflict-free)
constexpr int TILE = BLK * H;   // 5120 floats per tile

// packed-weight layout in d_ws (floats) — identical to validated R5-R8:
constexpr int WHH_OFF = 0;
constexpr int WIH_OFF = 1600;
constexpr int B_OFF   = 1760;

typedef float v2f __attribute__((ext_vector_type(2)));
__device__ __forceinline__ v2f splat2(float s) { v2f r; r.x = s; r.y = s; return r; }

// ---- exact path (bit-compatible with validated R3/R5-R8 kernels) ----
__device__ __forceinline__ float sigmoidf_stable(float z) {
    const float e = expf(-fabsf(z));
    const float n = (z >= 0.0f) ? 1.0f : e;
    return n / (1.0f + e);
}

// ---- fast path: native exp / rcp (validated R6-R8) ----
__device__ __forceinline__ float fsigmoid(float z) {
    const float e = __expf(-z);
    return __builtin_amdgcn_rcpf(1.0f + e);
}
__device__ __forceinline__ float ftanh(float z) {
    const float e = __expf(2.0f * z);
    return 1.0f - 2.0f * __builtin_amdgcn_rcpf(e + 1.0f);
}

constexpr float EPS_GUARD = 1e-4f;

__global__ __launch_bounds__(256) void pack_weights(
    const float* __restrict__ W_ih, const float* __restrict__ W_hh,
    const float* __restrict__ b_ih, const float* __restrict__ b_hh,
    float* __restrict__ ws)
{
    const int i = blockIdx.x * 256 + threadIdx.x;
    if (i < 400) {
        const int q = i / 20, k = i % 20;
#pragma unroll
        for (int g = 0; g < 4; ++g)
            ws[WHH_OFF + i * 4 + g] = W_hh[(g * 20 + q) * 20 + k];
    }
    if (i < 20) {
#pragma unroll
        for (int g = 0; g < 4; ++g) {
            ws[WIH_OFF + i * 8 + g]     = W_ih[(g * 20 + i) * 2 + 0];
            ws[WIH_OFF + i * 8 + 4 + g] = W_ih[(g * 20 + i) * 2 + 1];
            ws[B_OFF   + i * 4 + g]     = b_ih[g * 20 + i] + b_hh[g * 20 + i];
        }
    }
}

__global__ __launch_bounds__(BLK) void lstm_coord_kernel(
    const float* __restrict__ x,
    const float* __restrict__ hx,
    const float* __restrict__ cx,
    const float* __restrict__ u,
    const float* __restrict__ wsp,
    const float* __restrict__ W_dec,
    const float* __restrict__ b_dec,
    float* __restrict__ out)
{
    // LDS used ONLY to coalesce the h/c output stores.
    __shared__ float sH[BLK * RS];
    __shared__ float sC[BLK * RS];

    const int t = threadIdx.x;
    const size_t base = (size_t)blockIdx.x * TILE;
    const int b = blockIdx.x * BLK + t;
    const int row = t * RS;

    // ---- direct per-row register loads (no LDS, no barriers) ----
    const size_t rowbase = (size_t)b * H;
    v2f hv2[H];              // splatted for packed-FMA operand; live for fallback
    float cxv[H];
#pragma unroll
    for (int j = 0; j < 5; ++j) {
        const float4 hh = *reinterpret_cast<const float4*>(hx + rowbase + 4 * j);
        hv2[4 * j + 0] = splat2(hh.x); hv2[4 * j + 1] = splat2(hh.y);
        hv2[4 * j + 2] = splat2(hh.z); hv2[4 * j + 3] = splat2(hh.w);
        const float4 cc = *reinterpret_cast<const float4*>(cx + rowbase + 4 * j);
        cxv[4 * j + 0] = cc.x; cxv[4 * j + 1] = cc.y;
        cxv[4 * j + 2] = cc.z; cxv[4 * j + 3] = cc.w;
    }
    const float2 xv = *reinterpret_cast<const float2*>(x + 2 * (size_t)b);
    const v2f x0v = splat2(xv.x);
    const v2f x1v = splat2(xv.y);
    const float uv = u[b];

    // ---- FAST path: LSTM cell + fused decode ----
    // ROLLED q-loop (I$ fit): ops and their order per q are identical to the
    // validated R8 kernel -> bit-identical outputs.
    float l0 = b_dec[0], l1 = b_dec[1], l2 = b_dec[2];
#pragma unroll 1
    for (int q = 0; q < H; ++q) {
        v2f g01 = *reinterpret_cast<const v2f*>(wsp + B_OFF + 4 * q);
        v2f g23 = *reinterpret_cast<const v2f*>(wsp + B_OFF + 4 * q + 2);
        g01 = g01 + x0v * *reinterpret_cast<const v2f*>(wsp + WIH_OFF + 8 * q);
        g23 = g23 + x0v * *reinterpret_cast<const v2f*>(wsp + WIH_OFF + 8 * q + 2);
        g01 = g01 + x1v * *reinterpret_cast<const v2f*>(wsp + WIH_OFF + 8 * q + 4);
        g23 = g23 + x1v * *reinterpret_cast<const v2f*>(wsp + WIH_OFF + 8 * q + 6);
#pragma unroll
        for (int k = 0; k < H; ++k) {
            const v2f wp01 = *reinterpret_cast<const v2f*>(wsp + WHH_OFF + (q * 20 + k) * 4);
            const v2f wp23 = *reinterpret_cast<const v2f*>(wsp + WHH_OFF + (q * 20 + k) * 4 + 2);
            g01 = g01 + hv2[k] * wp01;
            g23 = g23 + hv2[k] * wp23;
        }
        const float gi = fsigmoid(g01.x);
        const float gf = fsigmoid(g01.y);
        const float gg = ftanh(g23.x);
        const float go = fsigmoid(g23.y);
        const float cq = gf * cxv[q] + gi * gg;
        const float hq = go * ftanh(cq);
        sC[row + q] = cq;       // own row only
        sH[row + q] = hq;       // own row only
        l0 += hq * W_dec[q];
        l1 += hq * W_dec[20 + q];
        l2 += hq * W_dec[40 + q];
    }

    // ---- fast softmax + inverse-CDF sample ----
    const float m = fmaxf(fmaxf(l0, l1), l2);
    const float s = __expf(l0 - m) + __expf(l1 - m) + __expf(l2 - m);
    const float lse = m + __logf(s);
    const float lp0 = l0 - lse, lp1 = l1 - lse, lp2 = l2 - lse;
    const float p0 = __expf(lp0), p1 = __expf(lp1), p2 = __expf(lp2);
    const float c0 = p0;
    const float c1 = c0 + p1;
    const float c2 = c1 + p2;
    int acti = (int)(c0 < uv) + (int)(c1 < uv) + (int)(c2 < uv);
    acti = acti > 2 ? 2 : acti;
    float act = (float)acti;
    float slp = (acti == 0) ? lp0 : ((acti == 1) ? lp1 : lp2);

    // ---- guard: near a fast-cdf boundary -> redo with exact libm path ----
    const float d0 = fabsf(c0 - uv), d1 = fabsf(c1 - uv), d2 = fabsf(c2 - uv);
    const bool risky = fminf(fminf(d0, d1), d2) < EPS_GUARD;
    if (risky) {
        const float* cxr = cx + rowbase;   // original cx
        float l0e = b_dec[0], l1e = b_dec[1], l2e = b_dec[2];
#pragma unroll 1
        for (int q = 0; q < H; ++q) {
            v2f g01 = *reinterpret_cast<const v2f*>(wsp + B_OFF + 4 * q);
            v2f g23 = *reinterpret_cast<const v2f*>(wsp + B_OFF + 4 * q + 2);
            g01 = g01 + x0v * *reinterpret_cast<const v2f*>(wsp + WIH_OFF + 8 * q);
            g23 = g23 + x0v * *reinterpret_cast<const v2f*>(wsp + WIH_OFF + 8 * q + 2);
            g01 = g01 + x1v * *reinterpret_cast<const v2f*>(wsp + WIH_OFF + 8 * q + 4);
            g23 = g23 + x1v * *reinterpret_cast<const v2f*>(wsp + WIH_OFF + 8 * q + 6);
#pragma unroll
            for (int k = 0; k < H; ++k) {
                const v2f wp01 = *reinterpret_cast<const v2f*>(wsp + WHH_OFF + (q * 20 + k) * 4);
                const v2f wp23 = *reinterpret_cast<const v2f*>(wsp + WHH_OFF + (q * 20 + k) * 4 + 2);
                g01 = g01 + hv2[k] * wp01;
                g23 = g23 + hv2[k] * wp23;
            }
            const float gi = sigmoidf_stable(g01.x);
            const float gf = sigmoidf_stable(g01.y);
            const float gg = tanhf(g23.x);
            const float go = sigmoidf_stable(g23.y);
            const float cq = gf * cxr[q] + gi * gg;
            const float hq = go * tanhf(cq);
            l0e += hq * W_dec[q];
            l1e += hq * W_dec[20 + q];
            l2e += hq * W_dec[40 + q];
        }
        const float me = fmaxf(fmaxf(l0e, l1e), l2e);
        const float se = expf(l0e - me) + expf(l1e - me) + expf(l2e - me);
        const float lsee = me + logf(se);
        const float lp0e = l0e - lsee, lp1e = l1e - lsee, lp2e = l2e - lsee;
        const float p0e = expf(lp0e), p1e = expf(lp1e), p2e = expf(lp2e);
        const float c0e = p0e;
        const float c1e = c0e + p1e;
        const float c2e = c1e + p2e;
        int ae = (int)(c0e < uv) + (int)(c1e < uv) + (int)(c2e < uv);
        ae = ae > 2 ? 2 : ae;
        act = (float)ae;
        slp = (ae == 0) ? lp0e : ((ae == 1) ? lp1e : lp2e);
    }

    out[b] = act;
    out[(size_t)BATCH + b] = slp;

    __syncthreads();   // all rows of sH/sC finalized

    // ---- coalesced LDS->global stores of h/c tiles (verbatim R8) ----
    float* hout  = out + 2 * (size_t)BATCH;
    float* cout_ = hout + (size_t)H * BATCH;
#pragma unroll
    for (int j = 0; j < 5; ++j) {
        const int g = 4 * (t + BLK * j);
        float4 v, w;
#pragma unroll
        for (int e = 0; e < 4; ++e) {
            const int gg = g + e;
            (&v.x)[e] = sH[gg + gg / H];
            (&w.x)[e] = sC[gg + gg / H];
        }
        *reinterpret_cast<float4*>(hout  + base + g) = v;
        *reinterpret_cast<float4*>(cout_ + base + g) = w;
    }
}

extern "C" void kernel_launch(void* const* d_in, const int* in_sizes, int n_in,
                              void* d_out, int out_size, void* d_ws, size_t ws_size,
                              hipStream_t stream) {
    const float* x     = (const float*)d_in[0];
    const float* hx    = (const float*)d_in[1];
    const float* cx    = (const float*)d_in[2];
    const float* u     = (const float*)d_in[3];
    const float* W_ih  = (const float*)d_in[4];
    const float* W_hh  = (const float*)d_in[5];
    const float* b_ih  = (const float*)d_in[6];
    const float* b_hh  = (const float*)d_in[7];
    const float* W_dec = (const float*)d_in[8];
    const float* b_dec = (const float*)d_in[9];
    float* out = (float*)d_out;
    float* ws  = (float*)d_ws;

    pack_weights<<<2, 256, 0, stream>>>(W_ih, W_hh, b_ih, b_hh, ws);

    dim3 grid(BATCH / BLK), block(BLK);
    lstm_coord_kernel<<<grid, block, 0, stream>>>(
        x, hx, cx, u, ws, W_dec, b_dec, out);
}